// Round 5
// baseline (37.987 us; speedup 1.0000x reference)
//
#include <hip/hip_runtime.h>
#include <math.h>

// LIF neuron forward: x (B=64, T=100, F=4096) f32, log_alpha scalar.
// u = alpha*u + x_t ; s = (u >= 1) ; u -= s. Outputs spikes (B,T,F) + mean.
//
// R5: phase-split to break load/store vmcnt coupling.
//   Phase 1: load+compute only; spike bits -> 4x u32 register mask;
//            loads double-buffered in 20-deep chunks (20 in flight/wave).
//   Phase 2: 100 back-to-back nontemporal dword stores (fire-and-forget).
// Parallelism is capped at B*F = 262144 threads (T serial per column):
// 1024 blocks = 4/CU = 16 waves/CU.

constexpr int T_STEPS = 100;
constexpr int CHUNK   = 20;
constexpr int NCHUNK  = T_STEPS / CHUNK;      // 5
constexpr int F       = 4096;
constexpr int BATCH   = 64;
constexpr int NBLOCKS = BATCH * F / 256;      // 1024
constexpr long long TOTAL = (long long)BATCH * T_STEPS * F;  // 26,214,400

__global__ __launch_bounds__(256)
void lif_fwd(const float* __restrict__ x,
             const float* __restrict__ log_alpha,
             float*       __restrict__ out,
             unsigned int* __restrict__ blk_cnt) {
    int idx  = blockIdx.x * 256 + threadIdx.x;   // 0 .. 262143
    int b    = idx >> 12;                        // batch
    int f    = idx & 4095;                       // feature
    size_t base = (size_t)b * T_STEPS * F + f;

    // alpha = sigmoid(log_alpha), computed in double -> correctly rounded f32
    double la = (double)log_alpha[0];
    float alpha = (float)(1.0 / (1.0 + exp(-la)));

    float u = 0.f;
    unsigned int mask[4] = {0u, 0u, 0u, 0u};

    float bufA[CHUNK], bufB[CHUNK];

    // prologue: load chunk 0
    #pragma unroll
    for (int j = 0; j < CHUNK; ++j)
        bufA[j] = x[base + (size_t)j * F];

    #pragma unroll
    for (int c = 0; c < NCHUNK; ++c) {
        float* cur = (c & 1) ? bufB : bufA;
        float* nxt = (c & 1) ? bufA : bufB;
        // issue next chunk's loads before consuming current chunk
        if (c + 1 < NCHUNK) {
            #pragma unroll
            for (int j = 0; j < CHUNK; ++j)
                nxt[j] = x[base + (size_t)((c + 1) * CHUNK + j) * F];
        }
        #pragma unroll
        for (int j = 0; j < CHUNK; ++j) {
            int t = c * CHUNK + j;
            // explicit non-fused mul+add to match numpy/XLA-CPU rounding
            u = __fadd_rn(__fmul_rn(alpha, u), cur[j]);
            unsigned int bit = (u >= 1.0f) ? 1u : 0u;
            mask[t >> 5] |= bit << (t & 31);
            u -= (u >= 1.0f) ? 1.0f : 0.0f;
        }
    }

    // phase 2: pure store stream, no waits in between
    #pragma unroll
    for (int t = 0; t < T_STEPS; ++t) {
        float s = ((mask[t >> 5] >> (t & 31)) & 1u) ? 1.0f : 0.0f;
        __builtin_nontemporal_store(s, &out[base + (size_t)t * F]);
    }

    unsigned int c = (unsigned)__popc(mask[0]) + (unsigned)__popc(mask[1])
                   + (unsigned)__popc(mask[2]) + (unsigned)__popc(mask[3]);

    // wave (64-lane) reduction of spike count
    for (int off = 32; off > 0; off >>= 1)
        c += __shfl_down(c, off, 64);

    __shared__ unsigned int wsum[4];
    int lane = threadIdx.x & 63;
    int wid  = threadIdx.x >> 6;
    if (lane == 0) wsum[wid] = c;
    __syncthreads();
    if (threadIdx.x == 0)
        blk_cnt[blockIdx.x] = wsum[0] + wsum[1] + wsum[2] + wsum[3];
}

__global__ __launch_bounds__(256)
void lif_rate(const unsigned int* __restrict__ blk_cnt,
              float* __restrict__ rate_out) {
    unsigned int c = 0;
    #pragma unroll
    for (int i = 0; i < NBLOCKS / 256; ++i)
        c += blk_cnt[threadIdx.x + i * 256];
    for (int off = 32; off > 0; off >>= 1)
        c += __shfl_down(c, off, 64);
    __shared__ unsigned int wsum[4];
    int lane = threadIdx.x & 63;
    int wid  = threadIdx.x >> 6;
    if (lane == 0) wsum[wid] = c;
    __syncthreads();
    if (threadIdx.x == 0) {
        unsigned int s = wsum[0] + wsum[1] + wsum[2] + wsum[3];
        rate_out[0] = (float)((double)s / (double)TOTAL);
    }
}

extern "C" void kernel_launch(void* const* d_in, const int* in_sizes, int n_in,
                              void* d_out, int out_size, void* d_ws, size_t ws_size,
                              hipStream_t stream) {
    const float* x  = (const float*)d_in[0];
    const float* la = (const float*)d_in[1];
    float* out = (float*)d_out;
    unsigned int* blk_cnt = (unsigned int*)d_ws;

    lif_fwd<<<NBLOCKS, 256, 0, stream>>>(x, la, out, blk_cnt);
    lif_rate<<<1, 256, 0, stream>>>(blk_cnt, out + TOTAL);
}